// Round 4
// baseline (163.990 us; speedup 1.0000x reference)
//
#include <hip/hip_runtime.h>

typedef unsigned short u16;
typedef unsigned int u32;
typedef __attribute__((ext_vector_type(8))) short short8;
typedef __attribute__((ext_vector_type(4))) float f32x4;

#define LOG_SQRT_2PI 0.9189385332046727f
#define NB 16
#define NL 512
#define NE 512
#define ZWIN 20.0f
#define MAXTB 32

__device__ __forceinline__ u16 f2bf(float x) {
    u32 u = __builtin_bit_cast(u32, x);
    u += 0x7fffu + ((u >> 16) & 1u);
    return (u16)(u >> 16);
}

__device__ __forceinline__ void gload_lds16(const u16* g, u16* l) {
    __builtin_amdgcn_global_load_lds(
        (__attribute__((address_space(1))) void*)(u16*)g,
        (__attribute__((address_space(3))) void*)l,
        16, 0, 0);
}

// ---------------- K1: means via cumsum; zero dotbuf; block 0 also reduces taps ----------------
__global__ void k_means(const int* __restrict__ dint, float* __restrict__ means,
                        float* __restrict__ dotbuf,
                        const float* __restrict__ wproj, const float* __restrict__ wd,
                        const float* __restrict__ bd, const float* __restrict__ bproj,
                        float* __restrict__ taps) {
    int b = blockIdx.x, l = threadIdx.x;  // 512 threads
    __shared__ float s[NL];
    __shared__ float red[4][8];
    if (b == 0) {
        float wp = wproj[l];
        float v[4] = {wp * wd[l * 3 + 0], wp * wd[l * 3 + 1], wp * wd[l * 3 + 2], wp * bd[l]};
        int lane = l & 63, w = l >> 6;
        #pragma unroll
        for (int i = 0; i < 4; i++) {
            float t = v[i];
            for (int m = 32; m; m >>= 1) t += __shfl_xor(t, m);
            if (lane == 0) red[i][w] = t;
        }
    }
    float d = (float)dint[b * NL + l];
    s[l] = d;
    dotbuf[b * NL + l] = 0.0f;
    __syncthreads();
    if (b == 0 && l < 4) {
        float t = 0.f;
        for (int w2 = 0; w2 < 8; w2++) t += red[l][w2];
        if (l == 3) t += bproj[0];
        taps[l] = t;
    }
    for (int off = 1; off < NL; off <<= 1) {
        float v = (l >= off) ? s[l - off] : 0.0f;
        __syncthreads();
        s[l] += v;
        __syncthreads();
    }
    means[b * NL + l] = s[l] - 0.5f * d;
}

// ---------------- K2: xc -> XcT[b][e][l] bf16 + partial dot(xc, wproj) ----------------
__global__ void k_xc(const float* __restrict__ x, const float* __restrict__ en,
                     const float* __restrict__ pt,
                     const float* __restrict__ wn, const float* __restrict__ bn,
                     const float* __restrict__ wq, const float* __restrict__ bq,
                     const float* __restrict__ wproj,
                     u16* __restrict__ XcT, float* __restrict__ dotbuf) {
    __shared__ u16 tile[64][66];
    int b = blockIdx.z;
    int l0 = blockIdx.y * 64, e0 = blockIdx.x * 64;
    int tid = threadIdx.x;         // 256
    int lr = tid >> 6, c = tid & 63;
    int e = e0 + c;
    float wn0 = wn[e * 3], wn1 = wn[e * 3 + 1], wn2 = wn[e * 3 + 2];
    float wq0 = wq[e * 3], wq1 = wq[e * 3 + 1], wq2 = wq[e * 3 + 2];
    float bias = bn[e] + bq[e];
    float wp = wproj[e];
    #pragma unroll 4
    for (int it = 0; it < 16; ++it) {
        int ll = lr * 16 + it;
        int l = l0 + ll;
        int base = b * NL;
        float em1 = (l > 0)   ? en[base + l - 1] : 0.f;
        float ev  = en[base + l];
        float ep1 = (l < 511) ? en[base + l + 1] : 0.f;
        float pm1 = (l > 0)   ? pt[base + l - 1] : 0.f;
        float pv  = pt[base + l];
        float pp1 = (l < 511) ? pt[base + l + 1] : 0.f;
        float v = x[((size_t)(base + l)) * NE + e]
                + wn0 * em1 + wn1 * ev + wn2 * ep1
                + wq0 * pm1 + wq1 * pv + wq2 * pp1 + bias;
        tile[ll][c] = f2bf(v);
        float s = v * wp;
        for (int m = 32; m; m >>= 1) s += __shfl_xor(s, m);
        if (c == 0) atomicAdd(&dotbuf[base + l], s);
    }
    __syncthreads();
    #pragma unroll 4
    for (int it = 0; it < 16; ++it) {
        int eo = lr + 4 * it;  // 0..63
        XcT[((size_t)b * NE + (e0 + eo)) * NL + l0 + c] = tile[c][eo];
    }
}

// ---------------- K3: ranges -> inv_std, A; per-(b,tblock) l-window table ----------------
__global__ void k_rw(const float* __restrict__ df, const int* __restrict__ lens,
                     const float* __restrict__ taps, const float* __restrict__ dotbuf,
                     const float* __restrict__ means,
                     float* __restrict__ inv_std, float* __restrict__ Aarr,
                     int2* __restrict__ win, int ntb) {
    int b = blockIdx.x, l = threadIdx.x;  // 512 threads
    __shared__ int slo[MAXTB], shi[MAXTB];
    if (l < ntb) { slo[l] = NL; shi[l] = -1; }
    __syncthreads();
    int base = b * NL;
    float dm1 = (l > 0)   ? df[base + l - 1] : 0.f;
    float d0  = df[base + l];
    float dp1 = (l < 511) ? df[base + l + 1] : 0.f;
    float lin = dotbuf[base + l] + taps[3]
              + taps[0] * dm1 + taps[1] * d0 + taps[2] * dp1;
    float r = (lin > 20.f) ? lin : log1pf(expf(lin));
    bool pad = (l >= lens[b]);
    if (pad) r = 1.0f;
    float sd = fmaxf(r, 0.001f);
    inv_std[base + l] = 1.0f / sd;
    Aarr[base + l] = pad ? -1e30f : (-logf(sd) - LOG_SQRT_2PI);
    if (!pad) {
        float m = means[base + l];
        float fl = m - ZWIN * sd - 1.0f;
        float fh = m + ZWIN * sd + 1.0f;
        for (int tb = 0; tb < ntb; ++tb) {
            float t_lo = tb * 128.0f + 0.5f, t_hi = tb * 128.0f + 127.5f;
            if (fl <= t_hi && fh >= t_lo) {
                atomicMin(&slo[tb], l);
                atomicMax(&shi[tb], l);
            }
        }
    }
    __syncthreads();
    if (l < ntb) win[b * MAXTB + l] = make_int2(slo[l], shi[l]);
}

// ---------------- K4: banded GEMM; computes rn in-block; e0==0 blocks write out_w ----------------
__global__ __launch_bounds__(256) void k_gemm(const u16* __restrict__ XcT,
                                              const float* __restrict__ frames,
                                              const float* __restrict__ means,
                                              const float* __restrict__ inv_std,
                                              const float* __restrict__ Aarr,
                                              const int2* __restrict__ win,
                                              float* __restrict__ out,
                                              float* __restrict__ wout, int T) {
    __shared__ float4 sq[NL];
    __shared__ float fts[128];
    __shared__ float part[2][128];
    __shared__ float rvs[128];
    __shared__ u16 At[2][128][32];
    __shared__ u16 Bt[2][128][32];
    int b = blockIdx.z;
    int t0 = blockIdx.y * 128;
    int e0 = blockIdx.x * 128;
    int tid = threadIdx.x;
    int lane = tid & 63, wid = tid >> 6;
    int wm = wid >> 1, wn = wid & 1;
    const u16* Bb = XcT + (size_t)b * NE * NL;

    for (int i = tid; i < NL; i += 256)
        sq[i] = make_float4(means[b * NL + i], inv_std[b * NL + i], Aarr[b * NL + i], 0.f);
    if (tid < 128) fts[tid] = (t0 + tid < T) ? frames[t0 + tid] : -1e9f;

    int2 w = win[b * MAXTB + blockIdx.y];
    int ks0 = 0, nst = 0;
    if (w.x <= w.y) { ks0 = w.x >> 5; nst = (w.y >> 5) - ks0 + 1; }

    __syncthreads();  // sq, fts ready

    // --- per-t normalizer: 2 threads per t sum the band ---
    {
        int tr = tid & 127, h = tid >> 7;
        float ftr = fts[tr];
        float s = 0.f;
        for (int l = w.x + h; l <= w.y; l += 2) {
            float4 q = sq[l];
            float z = (ftr - q.x) * q.y;
            s += __expf(fmaf(z, -0.5f * z, q.z));
        }
        part[h][tr] = s;
    }
    __syncthreads();
    if (tid < 128) rvs[tid] = 1.0f / (part[0][tid] + part[1][tid] + 1e-20f);
    __syncthreads();

    int ta = tid >> 1;        // A-row (t offset) this thread fills
    int ha = (tid & 1) * 16;  // which 16-col half
    float ft = fts[ta];
    float rv = rvs[ta];

    int srow = wid * 32 + (lane >> 2);
    int skc = (lane & 3) * 8;

    f32x4 acc[4][4];
    #pragma unroll
    for (int m = 0; m < 4; m++)
        #pragma unroll
        for (int n = 0; n < 4; n++)
            #pragma unroll
            for (int k = 0; k < 4; k++) acc[m][n][k] = 0.0f;

    auto stage = [&](int buf, int ks) {
        int l0 = ks * 32;
        const u16* gb = Bb + (size_t)(e0 + srow) * NL + l0 + skc;
        gload_lds16(gb, &Bt[buf][wid * 32][0]);
        gload_lds16(gb + 16 * NL, &Bt[buf][wid * 32 + 16][0]);
        u32 pk[8];
        #pragma unroll
        for (int jj = 0; jj < 8; ++jj) {
            float4 q0 = sq[l0 + ha + jj * 2];
            float4 q1 = sq[l0 + ha + jj * 2 + 1];
            float z0 = (ft - q0.x) * q0.y;
            float p0 = __expf(fmaf(z0, -0.5f * z0, q0.z)) * rv;
            float z1 = (ft - q1.x) * q1.y;
            float p1 = __expf(fmaf(z1, -0.5f * z1, q1.z)) * rv;
            pk[jj] = (u32)f2bf(p0) | ((u32)f2bf(p1) << 16);
        }
        *(uint4*)&At[buf][ta][ha]     = make_uint4(pk[0], pk[1], pk[2], pk[3]);
        *(uint4*)&At[buf][ta][ha + 8] = make_uint4(pk[4], pk[5], pk[6], pk[7]);
    };

    int fr = lane & 15, fk = (lane >> 4) * 8;
    if (nst > 0) {
        stage(0, ks0);
        for (int s = 0; s < nst; ++s) {
            __syncthreads();  // buf[s&1] (ds_writes + gload_lds) visible
            if (s + 1 < nst) stage((s + 1) & 1, ks0 + s + 1);
            int buf = s & 1;
            short8 a[4], bb[4];
            #pragma unroll
            for (int m = 0; m < 4; m++)
                a[m] = *(const short8*)&At[buf][wm * 64 + m * 16 + fr][fk];
            #pragma unroll
            for (int n = 0; n < 4; n++)
                bb[n] = *(const short8*)&Bt[buf][wn * 64 + n * 16 + fr][fk];
            #pragma unroll
            for (int m = 0; m < 4; m++)
                #pragma unroll
                for (int n = 0; n < 4; n++)
                    acc[m][n] = __builtin_amdgcn_mfma_f32_16x16x32_bf16(a[m], bb[n], acc[m][n], 0, 0, 0);
        }
    }

    // --- C-write ---
    int r4 = (lane >> 4) * 4;
    #pragma unroll
    for (int m = 0; m < 4; m++) {
        int tb2 = t0 + wm * 64 + m * 16 + r4;
        #pragma unroll
        for (int j = 0; j < 4; j++) {
            int t = tb2 + j;
            if (t < T) {
                float* orow = out + ((size_t)b * T + t) * NE + e0 + wn * 64 + (lane & 15);
                #pragma unroll
                for (int n = 0; n < 4; n++) orow[n * 16] = acc[m][n][j];
            }
        }
    }

    // --- out_w epilogue (e-block 0 only): zeros outside K-step band, exp*rn inside ---
    if (e0 == 0 && t0 < T) {
        int tcnt = T - t0; if (tcnt > 128) tcnt = 128;
        int lo = tid >> 3;          // l mod 32
        int tb8 = (tid & 7) * 16;   // 16 consecutive t per thread
        int lband_lo = ks0 * 32, lband_hi = (ks0 + nst) * 32;  // [lo, hi)
        bool full = (tb8 + 16 <= tcnt);
        #pragma unroll 2
        for (int k = 0; k < 16; ++k) {
            int l = lo + k * 32;
            float* dst = wout + ((size_t)b * NL + l) * T + t0 + tb8;
            if (l >= lband_lo && l < lband_hi) {
                float4 q = sq[l];
                if (full) {
                    #pragma unroll
                    for (int tt = 0; tt < 16; ++tt) {
                        float z = (fts[tb8 + tt] - q.x) * q.y;
                        dst[tt] = __expf(fmaf(z, -0.5f * z, q.z)) * rvs[tb8 + tt];
                    }
                } else {
                    for (int tt = 0; tt + tb8 < tcnt; ++tt) {
                        float z = (fts[tb8 + tt] - q.x) * q.y;
                        dst[tt] = __expf(fmaf(z, -0.5f * z, q.z)) * rvs[tb8 + tt];
                    }
                }
            } else {
                if (full) {
                    float4 z4 = make_float4(0.f, 0.f, 0.f, 0.f);
                    #pragma unroll
                    for (int v = 0; v < 4; ++v) ((float4*)dst)[v] = z4;
                } else {
                    for (int tt = 0; tt + tb8 < tcnt; ++tt) dst[tt] = 0.f;
                }
            }
        }
    }
}

extern "C" void kernel_launch(void* const* d_in, const int* in_sizes, int n_in,
                              void* d_out, int out_size, void* d_ws, size_t ws_size,
                              hipStream_t stream) {
    const float* x      = (const float*)d_in[0];
    const float* df     = (const float*)d_in[1];
    const int*   dint   = (const int*)d_in[2];
    const float* en     = (const float*)d_in[3];
    const float* pt     = (const float*)d_in[4];
    const int*   lens   = (const int*)d_in[5];
    const float* frames = (const float*)d_in[6];
    const float* wd     = (const float*)d_in[7];
    const float* bd     = (const float*)d_in[8];
    const float* wn     = (const float*)d_in[9];
    const float* bn     = (const float*)d_in[10];
    const float* wq     = (const float*)d_in[11];
    const float* bq     = (const float*)d_in[12];
    const float* wproj  = (const float*)d_in[13];
    const float* bproj  = (const float*)d_in[14];

    int T = in_sizes[6];
    int ntb = (T + 127) / 128;   // <= 32

    char* ws = (char*)d_ws;
    float* taps    = (float*)(ws);             // 4 floats (256 B slot)
    float* means   = (float*)(ws + 256);       // B*L
    float* inv_std = (float*)(ws + 33024);     // B*L
    float* Aarr    = (float*)(ws + 65792);     // B*L
    float* dotbuf  = (float*)(ws + 98560);     // B*L
    int2*  win     = (int2*)(ws + 131328);     // B*MAXTB
    u16*   XcT     = (u16*)(ws + 135424);      // B*E*L bf16 = 8.39 MB

    float* out_up = (float*)d_out;                 // (B,T,E)
    float* out_w  = out_up + (size_t)NB * T * NE;  // (B,L,T)

    k_means<<<dim3(NB), dim3(512), 0, stream>>>(dint, means, dotbuf,
                                                wproj, wd, bd, bproj, taps);
    k_xc<<<dim3(8, 8, NB), dim3(256), 0, stream>>>(x, en, pt, wn, bn, wq, bq, wproj,
                                                   XcT, dotbuf);
    k_rw<<<dim3(NB), dim3(512), 0, stream>>>(df, lens, taps, dotbuf, means,
                                             inv_std, Aarr, win, ntb);
    k_gemm<<<dim3(4, ntb, NB), dim3(256), 0, stream>>>(XcT, frames, means, inv_std,
                                                       Aarr, win, out_up, out_w, T);
}

// Round 5
// 65.174 us; speedup vs baseline: 2.5162x; 2.5162x over previous
//
#include <hip/hip_runtime.h>

typedef unsigned short u16;
typedef unsigned int u32;
typedef __attribute__((ext_vector_type(8))) short short8;
typedef __attribute__((ext_vector_type(4))) float f32x4;

#define LOG_SQRT_2PI 0.9189385332046727f
#define NB 16
#define NL 512
#define NE 512
#define ZWIN 20.0f
#define MAXTB 32

__device__ __forceinline__ u16 f2bf(float x) {
    u32 u = __builtin_bit_cast(u32, x);
    u += 0x7fffu + ((u >> 16) & 1u);
    return (u16)(u >> 16);
}

__device__ __forceinline__ void gload_lds16(const u16* g, u16* l) {
    __builtin_amdgcn_global_load_lds(
        (__attribute__((address_space(1))) void*)(u16*)g,
        (__attribute__((address_space(3))) void*)l,
        16, 0, 0);
}

// ---------------- K1: means via cumsum; zero dotbuf; block 0 also reduces taps ----------------
__global__ void k_means(const int* __restrict__ dint, float* __restrict__ means,
                        float* __restrict__ dotbuf,
                        const float* __restrict__ wproj, const float* __restrict__ wd,
                        const float* __restrict__ bd, const float* __restrict__ bproj,
                        float* __restrict__ taps) {
    int b = blockIdx.x, l = threadIdx.x;  // 512 threads
    __shared__ float s[NL];
    __shared__ float red[4][8];
    if (b == 0) {
        float wp = wproj[l];
        float v[4] = {wp * wd[l * 3 + 0], wp * wd[l * 3 + 1], wp * wd[l * 3 + 2], wp * bd[l]};
        int lane = l & 63, w = l >> 6;
        #pragma unroll
        for (int i = 0; i < 4; i++) {
            float t = v[i];
            for (int m = 32; m; m >>= 1) t += __shfl_xor(t, m);
            if (lane == 0) red[i][w] = t;
        }
    }
    float d = (float)dint[b * NL + l];
    s[l] = d;
    dotbuf[b * NL + l] = 0.0f;
    __syncthreads();
    if (b == 0 && l < 4) {
        float t = 0.f;
        for (int w2 = 0; w2 < 8; w2++) t += red[l][w2];
        if (l == 3) t += bproj[0];
        taps[l] = t;
    }
    for (int off = 1; off < NL; off <<= 1) {
        float v = (l >= off) ? s[l - off] : 0.0f;
        __syncthreads();
        s[l] += v;
        __syncthreads();
    }
    means[b * NL + l] = s[l] - 0.5f * d;
}

// ---------------- K2: xc -> XcT[b][e][l] bf16 + partial dot(xc, wproj) ----------------
__global__ void k_xc(const float* __restrict__ x, const float* __restrict__ en,
                     const float* __restrict__ pt,
                     const float* __restrict__ wn, const float* __restrict__ bn,
                     const float* __restrict__ wq, const float* __restrict__ bq,
                     const float* __restrict__ wproj,
                     u16* __restrict__ XcT, float* __restrict__ dotbuf) {
    __shared__ u16 tile[64][66];
    int b = blockIdx.z;
    int l0 = blockIdx.y * 64, e0 = blockIdx.x * 64;
    int tid = threadIdx.x;         // 256
    int lr = tid >> 6, c = tid & 63;
    int e = e0 + c;
    float wn0 = wn[e * 3], wn1 = wn[e * 3 + 1], wn2 = wn[e * 3 + 2];
    float wq0 = wq[e * 3], wq1 = wq[e * 3 + 1], wq2 = wq[e * 3 + 2];
    float bias = bn[e] + bq[e];
    float wp = wproj[e];
    #pragma unroll 4
    for (int it = 0; it < 16; ++it) {
        int ll = lr * 16 + it;
        int l = l0 + ll;
        int base = b * NL;
        float em1 = (l > 0)   ? en[base + l - 1] : 0.f;
        float ev  = en[base + l];
        float ep1 = (l < 511) ? en[base + l + 1] : 0.f;
        float pm1 = (l > 0)   ? pt[base + l - 1] : 0.f;
        float pv  = pt[base + l];
        float pp1 = (l < 511) ? pt[base + l + 1] : 0.f;
        float v = x[((size_t)(base + l)) * NE + e]
                + wn0 * em1 + wn1 * ev + wn2 * ep1
                + wq0 * pm1 + wq1 * pv + wq2 * pp1 + bias;
        tile[ll][c] = f2bf(v);
        float s = v * wp;
        for (int m = 32; m; m >>= 1) s += __shfl_xor(s, m);
        if (c == 0) atomicAdd(&dotbuf[base + l], s);
    }
    __syncthreads();
    #pragma unroll 4
    for (int it = 0; it < 16; ++it) {
        int eo = lr + 4 * it;  // 0..63
        XcT[((size_t)b * NE + (e0 + eo)) * NL + l0 + c] = tile[c][eo];
    }
}

// ---------------- K3: ranges -> inv_std, A; per-(b,tblock) l-window table ----------------
__global__ void k_rw(const float* __restrict__ df, const int* __restrict__ lens,
                     const float* __restrict__ taps, const float* __restrict__ dotbuf,
                     const float* __restrict__ means,
                     float* __restrict__ inv_std, float* __restrict__ Aarr,
                     int2* __restrict__ win, int ntb) {
    int b = blockIdx.x, l = threadIdx.x;  // 512 threads
    __shared__ int slo[MAXTB], shi[MAXTB];
    if (l < ntb) { slo[l] = NL; shi[l] = -1; }
    __syncthreads();
    int base = b * NL;
    float dm1 = (l > 0)   ? df[base + l - 1] : 0.f;
    float d0  = df[base + l];
    float dp1 = (l < 511) ? df[base + l + 1] : 0.f;
    float lin = dotbuf[base + l] + taps[3]
              + taps[0] * dm1 + taps[1] * d0 + taps[2] * dp1;
    float r = (lin > 20.f) ? lin : log1pf(expf(lin));
    bool pad = (l >= lens[b]);
    if (pad) r = 1.0f;
    float sd = fmaxf(r, 0.001f);
    inv_std[base + l] = 1.0f / sd;
    Aarr[base + l] = pad ? -1e30f : (-logf(sd) - LOG_SQRT_2PI);
    if (!pad) {
        float m = means[base + l];
        float fl = m - ZWIN * sd - 1.0f;
        float fh = m + ZWIN * sd + 1.0f;
        for (int tb = 0; tb < ntb; ++tb) {
            float t_lo = tb * 128.0f + 0.5f, t_hi = tb * 128.0f + 127.5f;
            if (fl <= t_hi && fh >= t_lo) {
                atomicMin(&slo[tb], l);
                atomicMax(&shi[tb], l);
            }
        }
    }
    __syncthreads();
    if (l < ntb) win[b * MAXTB + l] = make_int2(slo[l], shi[l]);
}

// ---------------- K4: banded GEMM; rn in-block; out_w rows split across e-blocks ----------------
__global__ __launch_bounds__(256) void k_gemm(const u16* __restrict__ XcT,
                                              const float* __restrict__ frames,
                                              const float* __restrict__ means,
                                              const float* __restrict__ inv_std,
                                              const float* __restrict__ Aarr,
                                              const int2* __restrict__ win,
                                              float* __restrict__ out,
                                              float* __restrict__ wout, int T) {
    __shared__ float4 sq[NL];
    __shared__ float fts[128];
    __shared__ float part[2][128];
    __shared__ float rvs[128];
    __shared__ u16 At[2][128][32];
    __shared__ u16 Bt[2][128][32];
    int b = blockIdx.z;
    int t0 = blockIdx.y * 128;
    int e0 = blockIdx.x * 128;
    int tid = threadIdx.x;
    int lane = tid & 63, wid = tid >> 6;
    int wm = wid >> 1, wn = wid & 1;
    const u16* Bb = XcT + (size_t)b * NE * NL;

    for (int i = tid; i < NL; i += 256)
        sq[i] = make_float4(means[b * NL + i], inv_std[b * NL + i], Aarr[b * NL + i], 0.f);
    if (tid < 128) fts[tid] = (t0 + tid < T) ? frames[t0 + tid] : -1e9f;

    int2 w = win[b * MAXTB + blockIdx.y];
    int ks0 = 0, nst = 0;
    if (w.x <= w.y) { ks0 = w.x >> 5; nst = (w.y >> 5) - ks0 + 1; }

    __syncthreads();  // sq, fts ready

    // --- per-t normalizer: 2 threads per t sum the band ---
    {
        int tr = tid & 127, h = tid >> 7;
        float ftr = fts[tr];
        float s = 0.f;
        for (int l = w.x + h; l <= w.y; l += 2) {
            float4 q = sq[l];
            float z = (ftr - q.x) * q.y;
            s += __expf(fmaf(z, -0.5f * z, q.z));
        }
        part[h][tr] = s;
    }
    __syncthreads();
    if (tid < 128) rvs[tid] = 1.0f / (part[0][tid] + part[1][tid] + 1e-20f);
    __syncthreads();

    int ta = tid >> 1;        // A-row (t offset) this thread fills
    int ha = (tid & 1) * 16;  // which 16-col half
    float ft = fts[ta];
    float rv = rvs[ta];

    int srow = wid * 32 + (lane >> 2);
    int skc = (lane & 3) * 8;

    f32x4 acc[4][4];
    #pragma unroll
    for (int m = 0; m < 4; m++)
        #pragma unroll
        for (int n = 0; n < 4; n++)
            #pragma unroll
            for (int k = 0; k < 4; k++) acc[m][n][k] = 0.0f;

    auto stage = [&](int buf, int ks) {
        int l0 = ks * 32;
        const u16* gb = Bb + (size_t)(e0 + srow) * NL + l0 + skc;
        gload_lds16(gb, &Bt[buf][wid * 32][0]);
        gload_lds16(gb + 16 * NL, &Bt[buf][wid * 32 + 16][0]);
        u32 pk[8];
        #pragma unroll
        for (int jj = 0; jj < 8; ++jj) {
            float4 q0 = sq[l0 + ha + jj * 2];
            float4 q1 = sq[l0 + ha + jj * 2 + 1];
            float z0 = (ft - q0.x) * q0.y;
            float p0 = __expf(fmaf(z0, -0.5f * z0, q0.z)) * rv;
            float z1 = (ft - q1.x) * q1.y;
            float p1 = __expf(fmaf(z1, -0.5f * z1, q1.z)) * rv;
            pk[jj] = (u32)f2bf(p0) | ((u32)f2bf(p1) << 16);
        }
        *(uint4*)&At[buf][ta][ha]     = make_uint4(pk[0], pk[1], pk[2], pk[3]);
        *(uint4*)&At[buf][ta][ha + 8] = make_uint4(pk[4], pk[5], pk[6], pk[7]);
    };

    int fr = lane & 15, fk = (lane >> 4) * 8;
    if (nst > 0) {
        stage(0, ks0);
        for (int s = 0; s < nst; ++s) {
            __syncthreads();  // buf[s&1] (ds_writes + gload_lds) visible
            if (s + 1 < nst) stage((s + 1) & 1, ks0 + s + 1);
            int buf = s & 1;
            short8 a[4], bb[4];
            #pragma unroll
            for (int m = 0; m < 4; m++)
                a[m] = *(const short8*)&At[buf][wm * 64 + m * 16 + fr][fk];
            #pragma unroll
            for (int n = 0; n < 4; n++)
                bb[n] = *(const short8*)&Bt[buf][wn * 64 + n * 16 + fr][fk];
            #pragma unroll
            for (int m = 0; m < 4; m++)
                #pragma unroll
                for (int n = 0; n < 4; n++)
                    acc[m][n] = __builtin_amdgcn_mfma_f32_16x16x32_bf16(a[m], bb[n], acc[m][n], 0, 0, 0);
        }
    }

    // --- C-write ---
    int r4 = (lane >> 4) * 4;
    #pragma unroll
    for (int m = 0; m < 4; m++) {
        int tb2 = t0 + wm * 64 + m * 16 + r4;
        #pragma unroll
        for (int j = 0; j < 4; j++) {
            int t = tb2 + j;
            if (t < T) {
                float* orow = out + ((size_t)b * T + t) * NE + e0 + wn * 64 + (lane & 15);
                #pragma unroll
                for (int n = 0; n < 4; n++) orow[n * 16] = acc[m][n][j];
            }
        }
    }

    // --- out_w epilogue: this e-block writes rows [e0, e0+128), lane <-> t coalesced ---
    if (t0 < T) {
        int tcnt = T - t0; if (tcnt > 128) tcnt = 128;
        int rbeg = e0, rend = e0 + 128;
        int bl0 = ks0 * 32, bl1 = (ks0 + nst) * 32;   // K-step-aligned band [bl0, bl1)
        int ib0 = bl0 > rbeg ? bl0 : rbeg;
        int ib1 = bl1 < rend ? bl1 : rend;
        // zero-fill rows outside band: 32-lane groups, float4 across t
        int t4 = (tid & 31) * 4, rsub = tid >> 5;     // 8 rows per pass
        bool t4full = (t4 + 4 <= tcnt);
        float4 z4 = make_float4(0.f, 0.f, 0.f, 0.f);
        auto zfill = [&](int r0, int r1) {
            for (int l = r0 + rsub; l < r1; l += 8) {
                float* d = wout + ((size_t)b * NL + l) * T + t0 + t4;
                if (t4full) *(float4*)d = z4;
                else { for (int u = 0; u < 4 && t4 + u < tcnt; ++u) d[u] = 0.f; }
            }
        };
        if (ib0 >= ib1) {
            zfill(rbeg, rend);
        } else {
            zfill(rbeg, ib0);
            zfill(ib1, rend);
            int tt = tid & 127, half = tid >> 7;
            if (tt < tcnt) {
                float ftl = fts[tt], rvl = rvs[tt];
                float* dstc = wout + (size_t)b * NL * T + t0 + tt;
                for (int l = ib0 + half; l < ib1; l += 2) {
                    float4 q = sq[l];
                    float z = (ftl - q.x) * q.y;
                    dstc[(size_t)l * T] = __expf(fmaf(z, -0.5f * z, q.z)) * rvl;
                }
            }
        }
    }
}

extern "C" void kernel_launch(void* const* d_in, const int* in_sizes, int n_in,
                              void* d_out, int out_size, void* d_ws, size_t ws_size,
                              hipStream_t stream) {
    const float* x      = (const float*)d_in[0];
    const float* df     = (const float*)d_in[1];
    const int*   dint   = (const int*)d_in[2];
    const float* en     = (const float*)d_in[3];
    const float* pt     = (const float*)d_in[4];
    const int*   lens   = (const int*)d_in[5];
    const float* frames = (const float*)d_in[6];
    const float* wd     = (const float*)d_in[7];
    const float* bd     = (const float*)d_in[8];
    const float* wn     = (const float*)d_in[9];
    const float* bn     = (const float*)d_in[10];
    const float* wq     = (const float*)d_in[11];
    const float* bq     = (const float*)d_in[12];
    const float* wproj  = (const float*)d_in[13];
    const float* bproj  = (const float*)d_in[14];

    int T = in_sizes[6];
    int ntb = (T + 127) / 128;   // <= 32

    char* ws = (char*)d_ws;
    float* taps    = (float*)(ws);             // 4 floats (256 B slot)
    float* means   = (float*)(ws + 256);       // B*L
    float* inv_std = (float*)(ws + 33024);     // B*L
    float* Aarr    = (float*)(ws + 65792);     // B*L
    float* dotbuf  = (float*)(ws + 98560);     // B*L
    int2*  win     = (int2*)(ws + 131328);     // B*MAXTB
    u16*   XcT     = (u16*)(ws + 135424);      // B*E*L bf16 = 8.39 MB

    float* out_up = (float*)d_out;                 // (B,T,E)
    float* out_w  = out_up + (size_t)NB * T * NE;  // (B,L,T)

    k_means<<<dim3(NB), dim3(512), 0, stream>>>(dint, means, dotbuf,
                                                wproj, wd, bd, bproj, taps);
    k_xc<<<dim3(8, 8, NB), dim3(256), 0, stream>>>(x, en, pt, wn, bn, wq, bq, wproj,
                                                   XcT, dotbuf);
    k_rw<<<dim3(NB), dim3(512), 0, stream>>>(df, lens, taps, dotbuf, means,
                                             inv_std, Aarr, win, ntb);
    k_gemm<<<dim3(4, ntb, NB), dim3(256), 0, stream>>>(XcT, frames, means, inv_std,
                                                       Aarr, win, out_up, out_w, T);
}